// Round 3
// baseline (2028.706 us; speedup 1.0000x reference)
//
#include <hip/hip_runtime.h>

// ---------------------------------------------------------------------------
// TAOBAODurendal: 2-layer hetero GraphConv + temporal blend + link scoring.
// Round-3 design:
//  * Inputs AND outputs are f32 (per reference); on-device probe confirms and
//    also keeps a bf16 fallback path. Output carve uses element offsets so the
//    same code serves either element size.
//  * CSR build per launch (hist -> scan -> bucket), reused by both layers.
//  * seg-mean fused into the MFMA GEMM as a per-row gather loop.
//  * _sem_agg with R=1 is identity; Wp folded into relation weights;
//    link score collapses to dot(u*i, Wpost[:,0]+Wpost[:,1]) + sum(bpost).
// ---------------------------------------------------------------------------

#define NUSER 100000
#define NITEM 50000
#define CDIM  128
#define EDGES 1000000
#define LBL   200000

// element offsets inside d_out: [h | cur1_user | cur1_item | cur2_user | cur2_item]
#define OFF_C1U ((long)LBL)
#define OFF_C1I (OFF_C1U + (long)NUSER * CDIM)
#define OFF_C2U (OFF_C1I + (long)NITEM * CDIM)
#define OFF_C2I (OFF_C2U + (long)NUSER * CDIM)

typedef __bf16 bf16x8 __attribute__((ext_vector_type(8)));
typedef float  f32x4  __attribute__((ext_vector_type(4)));

// ---- dual-dtype scalar load -------------------------------------------------
__device__ __forceinline__ float ld1(const void* base, size_t idx, bool isf32) {
  return isf32 ? ((const float*)base)[idx] : (float)((const __bf16*)base)[idx];
}

// ---- dtype probe ------------------------------------------------------------
// f32 data: even 16-bit halves are random mantissa bits -> ~48%/sample show
// bf16-exponent > 0x85 (|v|>64). bf16 N(0,1) data never does. flag=1 for f32.
__global__ void probe_dtype_kernel(const unsigned short* __restrict__ x,
                                   int* __restrict__ flag) {
  int t = threadIdx.x;  // 256
  int bad = 0;
  for (int i = t * 2; i < 8192; i += 512) {
    int e = (x[i] >> 7) & 0xFF;
    if (e > 0x85) bad = 1;
  }
  if (bad) atomicOr(flag, 1);
}

// ---- CSR build --------------------------------------------------------------
__global__ __launch_bounds__(256) void hist_kernel(
    const int* __restrict__ dst_ui, const int* __restrict__ dst_iu,
    int* __restrict__ cntI, int* __restrict__ cntU) {
  int e = blockIdx.x * 256 + threadIdx.x;
  if (e < EDGES) {
    atomicAdd(&cntI[dst_ui[e]], 1);
    atomicAdd(&cntU[dst_iu[e]], 1);
  }
}

// single-block exclusive scan, writes off[0..n] and cur=off.
__global__ __launch_bounds__(1024) void scan_kernel(const int* __restrict__ cnt,
                                                    int* __restrict__ off,
                                                    int* __restrict__ cur,
                                                    int n) {
  __shared__ int wsums[16];
  __shared__ int carry_s;
  int t = threadIdx.x, lane = t & 63, w = t >> 6;
  if (t == 0) carry_s = 0;
  __syncthreads();
  for (int base = 0; base < n; base += 1024) {
    int i = base + t;
    int v = (i < n) ? cnt[i] : 0;
    int x = v;
#pragma unroll
    for (int s = 1; s < 64; s <<= 1) {
      int y = __shfl_up(x, s, 64);
      if (lane >= s) x += y;
    }
    if (lane == 63) wsums[w] = x;
    __syncthreads();
    int woff = 0;
    for (int ww = 0; ww < w; ++ww) woff += wsums[ww];
    int carry = carry_s;
    __syncthreads();
    int excl = carry + woff + x - v;
    if (i < n) { off[i] = excl; cur[i] = excl; }
    if (t == 1023) carry_s = excl + v;
    __syncthreads();
  }
  if (t == 0) off[n] = carry_s;
}

__global__ __launch_bounds__(256) void bucket_kernel(
    const int* __restrict__ src_ui, const int* __restrict__ dst_ui,
    const int* __restrict__ src_iu, const int* __restrict__ dst_iu,
    int* __restrict__ curI, int* __restrict__ curU,
    int* __restrict__ permI, int* __restrict__ permU) {
  int e = blockIdx.x * 256 + threadIdx.x;
  if (e < EDGES) {
    int p = atomicAdd(&curI[dst_ui[e]], 1);
    permI[p] = src_ui[e];
    int p2 = atomicAdd(&curU[dst_iu[e]], 1);
    permU[p2] = src_iu[e];
  }
}

// ---- weight prep ------------------------------------------------------------
__global__ __launch_bounds__(128) void prep_transpose_kernel(
    const void* __restrict__ W0, const void* __restrict__ W1,
    const void* __restrict__ W2, const void* __restrict__ W3,
    __bf16* __restrict__ T0, __bf16* __restrict__ T1,
    __bf16* __restrict__ T2, __bf16* __restrict__ T3,
    const int* __restrict__ flag) {
  bool f = flag[0] != 0;
  int k = blockIdx.x, n = threadIdx.x, y = blockIdx.y;
  const void* W = (y == 0) ? W0 : (y == 1) ? W1 : (y == 2) ? W2 : W3;
  __bf16* T = (y == 0) ? T0 : (y == 1) ? T1 : (y == 2) ? T2 : T3;
  T[n * CDIM + k] = (__bf16)ld1(W, (size_t)k * CDIM + n, f);
}

// Tt = (W @ Wp)^T, f32 accumulate, bf16 store.
__global__ __launch_bounds__(128) void prep_combine_kernel(
    const void* __restrict__ W0, const void* __restrict__ W1,
    const void* __restrict__ W2, const void* __restrict__ W3,
    const void* __restrict__ Wp1, const void* __restrict__ Wp2,
    __bf16* __restrict__ T0, __bf16* __restrict__ T1,
    __bf16* __restrict__ T2, __bf16* __restrict__ T3,
    const int* __restrict__ flag) {
  bool f = flag[0] != 0;
  int k = blockIdx.x, n = threadIdx.x, y = blockIdx.y;
  const void* W = (y == 0) ? W0 : (y == 1) ? W1 : (y == 2) ? W2 : W3;
  const void* Wp = (y < 2) ? Wp1 : Wp2;
  __bf16* T = (y == 0) ? T0 : (y == 1) ? T1 : (y == 2) ? T2 : T3;
  float s = 0.f;
#pragma unroll 4
  for (int j = 0; j < CDIM; ++j)
    s += ld1(W, (size_t)k * CDIM + j, f) * ld1(Wp, (size_t)j * CDIM + n, f);
  T[n * CDIM + k] = (__bf16)s;
}

__global__ void prep_misc_kernel(const void* __restrict__ Wpost,
                                 const void* __restrict__ bpost,
                                 const void* __restrict__ bp1,
                                 const void* __restrict__ bp2,
                                 float* __restrict__ wsum,
                                 float* __restrict__ bpf1,
                                 float* __restrict__ bpf2,
                                 const int* __restrict__ flag) {
  bool f = flag[0] != 0;
  int t = threadIdx.x;  // 128
  wsum[t] = ld1(Wpost, (size_t)t * 2, f) + ld1(Wpost, (size_t)t * 2 + 1, f);
  bpf1[t] = ld1(bp1, t, f);
  bpf2[t] = ld1(bp2, t, f);
  if (t == 0) wsum[CDIM] = ld1(bpost, 0, f) + ld1(bpost, 1, f);
}

// ---- fused gather(seg-mean) + dual-GEMM + bias + temporal blend -------------
// out = blend(past, mean_{CSR}(feat) @ WtN^T + X @ WtS^T + bias).
// One wave per 16-row tile. mfma_f32_16x16x32_bf16 layouts:
//   A: lane = A[m=lane&15][k=(lane>>4)*8+j]; B: lane = B[k=(lane>>4)*8+j][n=lane&15]
//   (Wt[n][k] storage); C/D: col=lane&15, row=(lane>>4)*4+reg (m89/m91-verified).
// feat/X/out may live in d_out (element offsets), dtype = runtime flag.
template <bool HAS_BIAS>
__global__ __launch_bounds__(256) void gather_gemm_kernel(
    const int* __restrict__ off, const int* __restrict__ perm,
    const void* __restrict__ featb, long featoff,
    const void* __restrict__ Xb, long xoff,
    const __bf16* __restrict__ WtN, const __bf16* __restrict__ WtS,
    const float* __restrict__ bias, const void* __restrict__ past,
    const int* __restrict__ snapp, const int* __restrict__ flag,
    void* __restrict__ outb, long outoff, int nRowTiles) {
  bool f32 = (flag[0] != 0);
  bool blend = (snapp[0] != 0);
  int lane = threadIdx.x & 63;
  int ln = lane & 15, q = lane >> 4;
  int wave = blockIdx.x * 4 + (threadIdx.x >> 6);
  int nW = gridDim.x * 4;
  size_t cq = (size_t)q * 8;
  for (int rt = wave; rt < nRowTiles; rt += nW) {
    int row = rt * 16 + ln;
    int beg = off[row], end = off[row + 1];
    float s[4][8];
#pragma unroll
    for (int a = 0; a < 4; ++a)
#pragma unroll
      for (int j = 0; j < 8; ++j) s[a][j] = 0.f;
    if (f32) {
      const float* fb = (const float*)featb + featoff + cq;
      for (int i = beg; i < end; ++i) {
        const float* fp = fb + (size_t)perm[i] * CDIM;
#pragma unroll
        for (int ks = 0; ks < 4; ++ks) {
          f32x4 lo = *(const f32x4*)(fp + ks * 32);
          f32x4 hi = *(const f32x4*)(fp + ks * 32 + 4);
#pragma unroll
          for (int j = 0; j < 4; ++j) {
            s[ks][j] += lo[j];
            s[ks][4 + j] += hi[j];
          }
        }
      }
    } else {
      const __bf16* fb = (const __bf16*)featb + featoff + cq;
      for (int i = beg; i < end; ++i) {
        const __bf16* fp = fb + (size_t)perm[i] * CDIM;
#pragma unroll
        for (int ks = 0; ks < 4; ++ks) {
          bf16x8 v = *(const bf16x8*)(fp + ks * 32);
#pragma unroll
          for (int j = 0; j < 8; ++j) s[ks][j] += (float)v[j];
        }
      }
    }
    float rc = 1.0f / fmaxf((float)(end - beg), 1.0f);
    bf16x8 a1[4], a2[4];
    size_t xb = (size_t)row * CDIM + cq;
#pragma unroll
    for (int ks = 0; ks < 4; ++ks) {
      bf16x8 t1, t2;
      if (f32) {
        const float* xp = (const float*)Xb + xoff + xb + ks * 32;
        f32x4 lo = *(const f32x4*)xp;
        f32x4 hi = *(const f32x4*)(xp + 4);
#pragma unroll
        for (int j = 0; j < 4; ++j) {
          t2[j] = (__bf16)lo[j];
          t2[4 + j] = (__bf16)hi[j];
        }
      } else {
        t2 = *(const bf16x8*)((const __bf16*)Xb + xoff + xb + ks * 32);
      }
#pragma unroll
      for (int j = 0; j < 8; ++j) t1[j] = (__bf16)(s[ks][j] * rc);
      a1[ks] = t1;
      a2[ks] = t2;
    }
    f32x4 d[8];
#pragma unroll
    for (int ct = 0; ct < 8; ++ct) d[ct] = (f32x4){0.f, 0.f, 0.f, 0.f};
#pragma unroll
    for (int ct = 0; ct < 8; ++ct) {
      const __bf16* bn = WtN + (size_t)(ct * 16 + ln) * CDIM + q * 8;
      const __bf16* bs = WtS + (size_t)(ct * 16 + ln) * CDIM + q * 8;
#pragma unroll
      for (int ks = 0; ks < 4; ++ks) {
        d[ct] = __builtin_amdgcn_mfma_f32_16x16x32_bf16(
            a1[ks], *(const bf16x8*)(bn + ks * 32), d[ct], 0, 0, 0);
        d[ct] = __builtin_amdgcn_mfma_f32_16x16x32_bf16(
            a2[ks], *(const bf16x8*)(bs + ks * 32), d[ct], 0, 0, 0);
      }
    }
#pragma unroll
    for (int ct = 0; ct < 8; ++ct) {
      int col = ct * 16 + ln;
      float bv = HAS_BIAS ? bias[col] : 0.0f;
#pragma unroll
      for (int r = 0; r < 4; ++r) {
        long orow = rt * 16 + q * 4 + r;
        float v = d[ct][r] + bv;
        if (blend)
          v = 0.05f * ld1(past, (size_t)orow * CDIM + col, f32) + 0.95f * v;
        size_t oidx = (size_t)(outoff + orow * CDIM + col);
        if (f32)
          ((float*)outb)[oidx] = v;
        else
          ((__bf16*)outb)[oidx] = (__bf16)v;
      }
    }
  }
}

// ---- link scoring -----------------------------------------------------------
// h[l] = dot(u2[ls]*i2[ld], wsum) + bsum.  16 lanes per label, 8 ch each.
__global__ __launch_bounds__(256) void score_kernel(
    void* __restrict__ outb, const int* __restrict__ ls,
    const int* __restrict__ ld, const float* __restrict__ wsum,
    const int* __restrict__ flag) {
  bool f32 = (flag[0] != 0);
  int t = blockIdx.x * blockDim.x + threadIdx.x;
  int l = t >> 4;
  if (l >= LBL) return;
  size_t c8 = (size_t)(t & 15) << 3;
  float av[8], bv[8];
  if (f32) {
    const float* u = (const float*)outb + OFF_C2U + (size_t)ls[l] * CDIM + c8;
    const float* v = (const float*)outb + OFF_C2I + (size_t)ld[l] * CDIM + c8;
    f32x4 u0 = *(const f32x4*)u, u1 = *(const f32x4*)(u + 4);
    f32x4 v0 = *(const f32x4*)v, v1 = *(const f32x4*)(v + 4);
#pragma unroll
    for (int j = 0; j < 4; ++j) {
      av[j] = u0[j]; av[4 + j] = u1[j];
      bv[j] = v0[j]; bv[4 + j] = v1[j];
    }
  } else {
    bf16x8 a = *(const bf16x8*)((const __bf16*)outb + OFF_C2U +
                                (size_t)ls[l] * CDIM + c8);
    bf16x8 b = *(const bf16x8*)((const __bf16*)outb + OFF_C2I +
                                (size_t)ld[l] * CDIM + c8);
#pragma unroll
    for (int j = 0; j < 8; ++j) { av[j] = (float)a[j]; bv[j] = (float)b[j]; }
  }
  float p = 0.f;
#pragma unroll
  for (int j = 0; j < 8; ++j) p += av[j] * bv[j] * wsum[c8 + j];
  p += __shfl_xor(p, 1, 16);
  p += __shfl_xor(p, 2, 16);
  p += __shfl_xor(p, 4, 16);
  p += __shfl_xor(p, 8, 16);
  if ((t & 15) == 0) {
    float h = p + wsum[CDIM];
    if (f32)
      ((float*)outb)[l] = h;
    else
      ((__bf16*)outb)[l] = (__bf16)h;
  }
}

// ---------------------------------------------------------------------------
extern "C" void kernel_launch(void* const* d_in, const int* in_sizes, int n_in,
                              void* d_out, int out_size, void* d_ws,
                              size_t ws_size, hipStream_t stream) {
  const void* x_user = d_in[0];
  const void* x_item = d_in[1];
  const void* past1_user = d_in[2];
  const void* past1_item = d_in[3];
  const void* past2_user = d_in[4];
  const void* past2_item = d_in[5];
  const void* W1ui_n = d_in[6];
  const void* W1ui_s = d_in[7];
  const void* W1iu_n = d_in[8];
  const void* W1iu_s = d_in[9];
  const void* Wp1 = d_in[10];
  const void* bp1 = d_in[11];
  const void* W2ui_n = d_in[15];
  const void* W2ui_s = d_in[16];
  const void* W2iu_n = d_in[17];
  const void* W2iu_s = d_in[18];
  const void* Wp2 = d_in[19];
  const void* bp2 = d_in[20];
  const void* Wpost = d_in[24];
  const void* bpost = d_in[25];
  const int* src_ui = (const int*)d_in[26];
  const int* dst_ui = (const int*)d_in[27];
  const int* src_iu = (const int*)d_in[28];
  const int* dst_iu = (const int*)d_in[29];
  const int* lbl_src = (const int*)d_in[30];
  const int* lbl_dst = (const int*)d_in[31];
  const int* snap = (const int*)d_in[32];

  // ---- workspace carve (~10.2 MB), 256B-aligned sections ----
  size_t wo = 0;
  auto alloc = [&](size_t bytes) -> char* {
    char* p = (char*)d_ws + wo;
    wo += (bytes + 255) & ~(size_t)255;
    return p;
  };
  int* cntI = (int*)alloc(NITEM * 4);
  int* cntU = (int*)alloc(NUSER * 4);
  int* flag = (int*)alloc(256);
  size_t zeroBytes = wo;  // cntI + cntU + flag zeroed in one memset
  int* offI = (int*)alloc((NITEM + 1) * 4);
  int* offU = (int*)alloc((NUSER + 1) * 4);
  int* curI = (int*)alloc(NITEM * 4);
  int* curU = (int*)alloc(NUSER * 4);
  int* permI = (int*)alloc(EDGES * 4);
  int* permU = (int*)alloc(EDGES * 4);
  float* wsum = (float*)alloc(256 * 4);
  float* bpf1 = (float*)alloc(CDIM * 4);
  float* bpf2 = (float*)alloc(CDIM * 4);
  __bf16* wt0 = (__bf16*)alloc(8 * CDIM * CDIM * 2);
  __bf16* Wt[8];
  for (int i = 0; i < 8; ++i) Wt[i] = wt0 + (size_t)i * CDIM * CDIM;

  const int EB = (EDGES + 255) / 256;
  const int G_ITEM = (NITEM / 16 + 3) / 4;
  const int G_USER = (NUSER / 16 + 3) / 4;

  hipMemsetAsync(d_ws, 0, zeroBytes, stream);
  probe_dtype_kernel<<<1, 256, 0, stream>>>((const unsigned short*)x_user,
                                            flag);

  // CSR build (shared by both layers)
  hist_kernel<<<EB, 256, 0, stream>>>(dst_ui, dst_iu, cntI, cntU);
  scan_kernel<<<1, 1024, 0, stream>>>(cntI, offI, curI, NITEM);
  scan_kernel<<<1, 1024, 0, stream>>>(cntU, offU, curU, NUSER);
  bucket_kernel<<<EB, 256, 0, stream>>>(src_ui, dst_ui, src_iu, dst_iu, curI,
                                        curU, permI, permU);

  // weight prep: Wt0/1 = W1ui_{n,s}^T, Wt4/5 = W2ui_{n,s}^T,
  //              Wt2/3 = (W1iu_{n,s}@Wp1)^T, Wt6/7 = (W2iu_{n,s}@Wp2)^T
  prep_transpose_kernel<<<dim3(CDIM, 4), CDIM, 0, stream>>>(
      W1ui_n, W1ui_s, W2ui_n, W2ui_s, Wt[0], Wt[1], Wt[4], Wt[5], flag);
  prep_combine_kernel<<<dim3(CDIM, 4), CDIM, 0, stream>>>(
      W1iu_n, W1iu_s, W2iu_n, W2iu_s, Wp1, Wp2, Wt[2], Wt[3], Wt[6], Wt[7],
      flag);
  prep_misc_kernel<<<1, CDIM, 0, stream>>>(Wpost, bpost, bp1, bp2, wsum, bpf1,
                                           bpf2, flag);

  // layer 1
  gather_gemm_kernel<false><<<G_ITEM, 256, 0, stream>>>(
      offI, permI, x_user, 0, x_item, 0, Wt[0], Wt[1], nullptr, past1_item,
      snap, flag, d_out, OFF_C1I, NITEM / 16);
  gather_gemm_kernel<true><<<G_USER, 256, 0, stream>>>(
      offU, permU, x_item, 0, x_user, 0, Wt[2], Wt[3], bpf1, past1_user, snap,
      flag, d_out, OFF_C1U, NUSER / 16);
  // layer 2 (CSR reused; feats are our own outputs inside d_out)
  gather_gemm_kernel<false><<<G_ITEM, 256, 0, stream>>>(
      offI, permI, d_out, OFF_C1U, d_out, OFF_C1I, Wt[4], Wt[5], nullptr,
      past2_item, snap, flag, d_out, OFF_C2I, NITEM / 16);
  gather_gemm_kernel<true><<<G_USER, 256, 0, stream>>>(
      offU, permU, d_out, OFF_C1I, d_out, OFF_C1U, Wt[6], Wt[7], bpf2,
      past2_user, snap, flag, d_out, OFF_C2U, NUSER / 16);

  // scoring
  score_kernel<<<(LBL * 16) / 256, 256, 0, stream>>>(d_out, lbl_src, lbl_dst,
                                                     wsum, flag);
}